// Round 21
// baseline (18.801 us; speedup 1.0000x reference)
//
#include <hip/hip_runtime.h>
#include <math.h>

constexpr int TLEN = 512;
constexpr int CDIM = 64;
constexpr int BDIM = 2;

// Kernel 1: projections (R20, unchanged). hkt4 transposed + hqb row-major.
__global__ __launch_bounds__(256) void proj_kernel(
    const float* __restrict__ x, const float* __restrict__ pos,
    const float* __restrict__ W1, const float* __restrict__ b1,
    float4* __restrict__ hkt4, float* __restrict__ hqb)
{
    const int tid = threadIdx.x;
    const int r0g = blockIdx.x * 4;
    const int b   = r0g >> 9;
    const int t0  = r0g & (TLEN - 1);

    __shared__ float4 w1_s[64 * 64];          // 64 KiB swizzled W1 (Wk|Wq)
    __shared__ alignas(16) float x1s[4][128];
    __shared__ float hks[CDIM][5];            // +1 pad

    const float4* W1f4 = (const float4*)W1;
    #pragma unroll
    for (int m = tid; m < 64 * 64; m += 256) {
        const int c = m >> 6, e4 = m & 63;
        w1_s[c * 64 + (e4 ^ (c & 63))] = W1f4[c * 64 + e4];
    }
    #pragma unroll
    for (int e = tid; e < 4 * 128; e += 256) {
        const int r4 = e >> 7, d = e & 127;
        const int grow = r0g + r4;
        const int tt = grow & (TLEN - 1);
        x1s[r4][d] = (d < CDIM) ? pos[tt * CDIM + d]
                                : x[grow * CDIM + (d - CDIM)];
    }
    __syncthreads();

    {
        const int sub = tid >> 6, c = tid & 63;
        const int grow = r0g + sub;
        const float4* xv = (const float4*)x1s[sub];
        const float4* wb = w1_s + c * 64;
        const int sw = c & 63;
        float4 ak = make_float4(0.f, 0.f, 0.f, 0.f);
        float4 aq = ak;
        #pragma unroll
        for (int d4 = 0; d4 < 32; ++d4) {
            const float4 xx = xv[d4];
            const float4 wk = wb[d4 ^ sw];
            const float4 wq = wb[(32 + d4) ^ sw];
            ak.x = fmaf(xx.x, wk.x, ak.x); ak.y = fmaf(xx.y, wk.y, ak.y);
            ak.z = fmaf(xx.z, wk.z, ak.z); ak.w = fmaf(xx.w, wk.w, ak.w);
            aq.x = fmaf(xx.x, wq.x, aq.x); aq.y = fmaf(xx.y, wq.y, aq.y);
            aq.z = fmaf(xx.z, wq.z, aq.z); aq.w = fmaf(xx.w, wq.w, aq.w);
        }
        hks[c][sub] = (ak.x + ak.y) + (ak.z + ak.w);
        hqb[grow * CDIM + c] = (aq.x + aq.y) + (aq.z + aq.w) + b1[c];
    }
    __syncthreads();

    if (tid < 64) {                            // transpose-store f4 over c
        const int c4 = tid >> 2, tl = tid & 3;
        const float4 v = make_float4(hks[c4 * 4 + 0][tl], hks[c4 * 4 + 1][tl],
                                     hks[c4 * 4 + 2][tl], hks[c4 * 4 + 3][tl]);
        hkt4[(b * 16 + c4) * TLEN + t0 + tl] = v;
    }
}

// Kernel 2: attn, 256 blocks x 1024 threads, 4 rows/block in two independent
// halves: half0 = rows {p, 511-p}, half1 = {p+128, 383-p} (513 units each).
// Each half runs R20's two-pass score -> no-max softmax -> PV on its own
// pS/wreds slices. hkt/x read once per block instead of twice (traffic /2).
__global__ __launch_bounds__(1024, 4) void attn_kernel(
    const float* __restrict__ x,   const float* __restrict__ W2,
    const float* __restrict__ b2,  const float* __restrict__ Wv,
    const float4* __restrict__ hkt4, const float4* __restrict__ hqb4,
    float* __restrict__ out)
{
    const int tid = threadIdx.x;
    const int idx = blockIdx.x;               // 0..255
    const int b   = idx & 1;
    const int p   = idx >> 1;                 // 0..127
    // local rows: l=0/1 owned by half0 (short, long); l=2/3 by half1
    int rowArr[4];
    rowArr[0] = p;             rowArr[1] = (TLEN - 1) - p;      // 0..127, 384..511
    rowArr[2] = p + 128;       rowArr[3] = 383 - p;             // 128..255, 256..383

    const int half = tid >> 9;                 // 0/1
    const int jj   = tid & 511;                // column
    const int gw   = (tid >> 6) & 7;           // wave idx within half
    const int wg   = tid >> 6;                 // global wave idx 0..15
    const int lS   = half * 2;                 // this half's short row (local)
    const int lL   = half * 2 + 1;             // this half's long row (local)

    __shared__ float4 wv_s[64 * 16];           // 16 KiB swizzled Wv
    __shared__ float4 hq_s[4][16];             // hq+b1, 4 rows (from proj)
    __shared__ float4 w24_s[16];
    __shared__ alignas(16) float pS[4][TLEN];
    __shared__ float2 wreds[16];               // per-wave {sum_short, sum_long}
    __shared__ float pvs[4][8][CDIM];
    __shared__ alignas(16) float o_s[4][CDIM];

    // ---- stage Wv (swizzled), hq rows, W2 ----
    const float4* Wvf4 = (const float4*)Wv;
    #pragma unroll
    for (int m = tid; m < 64 * 16; m += 1024) {
        const int hh = m >> 4, e4 = m & 15;
        wv_s[hh * 16 + (e4 ^ (hh & 15))] = Wvf4[hh * 16 + e4];
    }
    if (tid < 64) {
        const int l = tid >> 4, e = tid & 15;
        hq_s[l][e] = hqb4[(b * TLEN + rowArr[l]) * 16 + e];
    } else if (tid < 80) {
        w24_s[tid - 64] = ((const float4*)W2)[tid - 64];
    }
    __syncthreads();

    // ---- scores -> exp -> pS + per-wave sums (two-pass per half) ----
    const float b2v = b2[0];
    const float4* hk4b = hkt4 + b * 16 * TLEN;
    const int rS = rowArr[lS], rL = rowArr[lL];

    float swS = 0.f, swL;
    {   // short row: wave-uniform causal skip within the half
        if ((gw << 6) <= rS) {
            const float4* hq4 = hq_s[lS];
            float4 acc = make_float4(0.f, 0.f, 0.f, 0.f);
            #pragma unroll
            for (int c4 = 0; c4 < 16; ++c4) {
                const float4 kk = hk4b[c4 * TLEN + jj];
                const float4 qq = hq4[c4];
                const float4 w2v = w24_s[c4];
                acc.x = fmaf(fmaxf(kk.x + qq.x, 0.f), w2v.x, acc.x);
                acc.y = fmaf(fmaxf(kk.y + qq.y, 0.f), w2v.y, acc.y);
                acc.z = fmaf(fmaxf(kk.z + qq.z, 0.f), w2v.z, acc.z);
                acc.w = fmaf(fmaxf(kk.w + qq.w, 0.f), w2v.w, acc.w);
            }
            const float sv = ((acc.x + acc.y) + (acc.z + acc.w) + b2v) * 0.125f;
            const float pt = (jj <= rS) ? __expf(sv) : 0.f;   // bounded scores
            pS[lS][jj] = pt;
            float sm = pt;
            #pragma unroll
            for (int off = 32; off > 0; off >>= 1)
                sm += __shfl_xor(sm, off);
            swS = sm;
        }
    }
    {   // long row: all waves of the half active
        const float4* hq4 = hq_s[lL];
        float4 acc = make_float4(0.f, 0.f, 0.f, 0.f);
        #pragma unroll
        for (int c4 = 0; c4 < 16; ++c4) {
            const float4 kk = hk4b[c4 * TLEN + jj];
            const float4 qq = hq4[c4];
            const float4 w2v = w24_s[c4];
            acc.x = fmaf(fmaxf(kk.x + qq.x, 0.f), w2v.x, acc.x);
            acc.y = fmaf(fmaxf(kk.y + qq.y, 0.f), w2v.y, acc.y);
            acc.z = fmaf(fmaxf(kk.z + qq.z, 0.f), w2v.z, acc.z);
            acc.w = fmaf(fmaxf(kk.w + qq.w, 0.f), w2v.w, acc.w);
        }
        const float sv = ((acc.x + acc.y) + (acc.z + acc.w) + b2v) * 0.125f;
        const float pt = (jj <= rL) ? __expf(sv) : 0.f;
        pS[lL][jj] = pt;
        float sm = pt;
        #pragma unroll
        for (int off = 32; off > 0; off >>= 1)
            sm += __shfl_xor(sm, off);
        swL = sm;
    }
    if ((tid & 63) == 0) wreds[wg] = make_float2(swS, swL);
    __syncthreads();                            // pS + wreds visible

    // ---- PV (unnormalized): each half its 2 rows; x loads shared in L1 ----
    const int h = tid & 63;
    const int g = gw;
    const float* xh = x + b * TLEN * CDIM + h;
    const int nj4 = (rL >> 2) + 1;
    float4 aS = make_float4(0.f, 0.f, 0.f, 0.f);
    float4 aL = aS;
    for (int j4 = g; j4 < nj4; j4 += 8) {
        const int j0 = j4 * 4;
        const float4 pLv = ((const float4*)pS[lL])[j4];  // LDS broadcast
        const float x0 = xh[j0 * CDIM];                  // coalesced
        const float x1 = xh[(j0 + 1) * CDIM];
        const float x2 = xh[(j0 + 2) * CDIM];
        const float x3 = xh[(j0 + 3) * CDIM];
        aL.x = fmaf(pLv.x, x0, aL.x); aL.y = fmaf(pLv.y, x1, aL.y);
        aL.z = fmaf(pLv.z, x2, aL.z); aL.w = fmaf(pLv.w, x3, aL.w);
        if (j0 <= rS) {                                  // wave-uniform
            const float4 pSv = ((const float4*)pS[lS])[j4];
            aS.x = fmaf(pSv.x, x0, aS.x); aS.y = fmaf(pSv.y, x1, aS.y);
            aS.z = fmaf(pSv.z, x2, aS.z); aS.w = fmaf(pSv.w, x3, aS.w);
        }
    }
    pvs[lS][g][h] = (aS.x + aS.y) + (aS.z + aS.w);
    pvs[lL][g][h] = (aL.x + aL.y) + (aL.z + aL.w);
    __syncthreads();
    if (tid < 256) {
        const int l = tid >> 6, hh = tid & 63;
        float o = pvs[l][0][hh];
        #pragma unroll
        for (int ww = 1; ww < 8; ++ww) o += pvs[l][ww][hh];
        // global exp-sum for local row l: half = l>>1, component = l&1
        const int base = (l >> 1) * 8;
        float gsum = 0.f;
        #pragma unroll
        for (int ww = 0; ww < 8; ++ww)
            gsum += (l & 1) ? wreds[base + ww].y : wreds[base + ww].x;
        o_s[l][hh] = o / gsum;
    }
    __syncthreads();
    if (tid < 256) {                           // out = o_l . Wv[h,:] (LDS)
        const int l = tid >> 6, hh = tid & 63;
        const float4* wb = wv_s + hh * 16;
        const int sw = hh & 15;
        const float4* o4 = (const float4*)o_s[l];
        float4 a = make_float4(0.f, 0.f, 0.f, 0.f);
        #pragma unroll
        for (int c4 = 0; c4 < 16; ++c4) {
            const float4 wwv = wb[c4 ^ sw];
            const float4 oo = o4[c4];
            a.x = fmaf(oo.x, wwv.x, a.x); a.y = fmaf(oo.y, wwv.y, a.y);
            a.z = fmaf(oo.z, wwv.z, a.z); a.w = fmaf(oo.w, wwv.w, a.w);
        }
        out[(b * TLEN + rowArr[l]) * CDIM + hh] = (a.x + a.y) + (a.z + a.w);
    }
}

extern "C" void kernel_launch(void* const* d_in, const int* in_sizes, int n_in,
                              void* d_out, int out_size, void* d_ws, size_t ws_size,
                              hipStream_t stream)
{
    const float* x   = (const float*)d_in[0];
    const float* pos = (const float*)d_in[1];
    const float* W1  = (const float*)d_in[2];
    const float* b1  = (const float*)d_in[3];
    const float* W2  = (const float*)d_in[4];
    const float* b2  = (const float*)d_in[5];
    const float* Wv  = (const float*)d_in[6];
    float* out = (float*)d_out;

    float4* hkt4 = (float4*)d_ws;                      // 256 KiB transposed hk
    float*  hqb  = (float*)d_ws + 4 * 16384;           // 256 KiB hq + b1

    proj_kernel<<<BDIM * TLEN / 4, 256, 0, stream>>>(x, pos, W1, b1, hkt4, hqb);
    attn_kernel<<<BDIM * TLEN / 4, 1024, 0, stream>>>(x, W2, b2, Wv,
                                                      hkt4, (const float4*)hqb,
                                                      out);
}